// Round 5
// baseline (269.257 us; speedup 1.0000x reference)
//
#include <hip/hip_runtime.h>
#include <climits>
#include <cmath>

// DetectPeaks: xcorr [16,1,256,8192] f32 -> (neighbor_score, topk_scores, topk_index), each [rows,3]
// rows = 4096, W = 8192.
// Round-9: INSTRUMENTED round. Rounds 0-4 pinned data consumption at ~0.9-1.2 TB/s across
// four structure families (LDS-DMA staging w/ 100KB/CU in-flight, chained, batched, fully
// uncoupled two-pass) -- structure and MLP are exonerated. Two live hypotheses:
//   (E) environment bandwidth ceiling ~1.1-1.3 TB/s (partition/path cap) -> we are AT roofline.
//   (K) canonical streaming would hit 3-6 TB/s here; all our kernels share a subtle defect.
// Per rigor: a ceiling claim needs a known-good kernel on the same buffers. bw_probe below IS
// the canonical 6.3 TB/s copy-ubench pattern (grid-stride float4, trivial compute) run on the
// exact input buffer. Its rocprof row is the decisive readout. It writes wave-maxes into the
// ws region that pass1 then fully overwrites -> zero correctness impact, bench metric pays
// +probe-duration this round only.

#define PW    8192
#define PNLAG (PW / 2)
#define BLOCK 256
#define NW    4                 // waves per block (pass 1)
#define J     8                 // float4 quads per lane: chunk = J*64*4 = 2048 elems
#define CHUNK 2048
#define CPR   4                 // chunks per row
#define PROBE_BLOCKS 2048

__device__ __forceinline__ bool better(float av, int ai, float bv, int bi) {
  return (av > bv) || ((av == bv) && (ai < bi));   // lax.top_k: ties -> lower index
}

__device__ __forceinline__ void insert3_full(float v, int i,
                                             float &v0, int &i0,
                                             float &v1, int &i1,
                                             float &v2, int &i2) {
  if (better(v, i, v2, i2)) {
    if (better(v, i, v1, i1)) {
      if (better(v, i, v0, i0)) {
        v2 = v1; i2 = i1; v1 = v0; i1 = i0; v0 = v; i0 = i;
      } else {
        v2 = v1; i2 = i1; v1 = v; i1 = i;
      }
    } else {
      v2 = v; i2 = i;
    }
  }
}

// Exact float ties between distinct lags have ~0 probability; strict > suffices.
// Candidates arrive in ascending-index order per lane => incumbent-wins keeps lower index.
__device__ __forceinline__ void insert3_fast(float c, int ci,
                                             float &v0, int &i0,
                                             float &v1, int &i1,
                                             float &v2, int &i2) {
  const bool b2 = c > v2;
  const bool b1 = c > v1;
  const bool b0 = c > v0;
  v2 = b1 ? v1 : (b2 ? c : v2);  i2 = b1 ? i1 : (b2 ? ci : i2);
  v1 = b0 ? v0 : (b1 ? c : v1);  i1 = b0 ? i0 : (b1 ? ci : i1);
  v0 = b0 ? c  : v0;             i0 = b0 ? ci : i0;
}

// ---- BW probe: canonical copy-ubench read pattern over the exact input buffer ----
// grid-stride float4, 16 iters/thread, independent addresses -> compiler pipelines loads.
// This is the known-good 6.3 TB/s pattern; its rocprof row measures THIS environment's
// achievable read BW on THIS buffer. Output (wave maxes) lands in ws[0..32KB), which
// peaks_pass1 fully overwrites afterwards.
__global__ __launch_bounds__(BLOCK)
void bw_probe(const float4* __restrict__ x, float* __restrict__ ws, int n4) {
  const int tid    = blockIdx.x * BLOCK + threadIdx.x;
  const int stride = gridDim.x * BLOCK;
  float m = -INFINITY;
  for (int i = tid; i < n4; i += stride) {
    const float4 v = x[i];
    m = fmaxf(m, fmaxf(fmaxf(v.x, v.y), fmaxf(v.z, v.w)));
  }
#pragma unroll
  for (int off = 32; off > 0; off >>= 1)
    m = fmaxf(m, __shfl_down(m, off));
  if ((threadIdx.x & 63) == 0)
    ws[blockIdx.x * NW + (threadIdx.x >> 6)] = m;   // [0, 32 KB) of ws; overwritten by pass1
}

__global__ __launch_bounds__(BLOCK, 4)
void peaks_pass1(const float* __restrict__ x, float* __restrict__ ws) {
  const int t     = threadIdx.x;
  const int lane  = t & 63;
  const int wave  = t >> 6;
  const int chunk = blockIdx.x * NW + wave;     // 0..16383, fully independent per wave
  const int row   = chunk >> 2;
  const int c     = chunk & 3;
  const float* __restrict__ xr = x + (size_t)row * PW;
  const int base  = c * CHUNK;

  // chunk-edge halos (row edges pad -inf per torch max_pool2d); wave-uniform loads
  const float edgeL = (base > 0)          ? xr[base - 1]     : -INFINITY;
  const float edgeR = (base + CHUNK < PW) ? xr[base + CHUNK] : -INFINITY;

  float4 q[J];
#pragma unroll
  for (int j = 0; j < J; ++j)
    q[j] = *(const float4*)(xr + base + (j * 64 + lane) * 4);

  float v0 = -INFINITY, v1 = -INFINITY, v2 = -INFINITY;
  int   i0 = INT_MAX,   i1 = INT_MAX,   i2 = INT_MAX;

#pragma unroll
  for (int j = 0; j < J; ++j) {
    const float4 v = q[j];

    // left halo = element p-1; right halo = element p+4
    float left = __shfl_up(v.w, 1);
    const float lf = (j == 0) ? edgeL : __shfl(q[j - 1].w, 63);
    if (lane == 0) left = lf;
    float right = __shfl_down(v.x, 1);
    const float rf = (j == J - 1) ? edgeR : __shfl(q[j + 1].x, 0);
    if (lane == 63) right = rf;

    const int p = base + (j * 64 + lane) * 4;   // first element index of this quad (in-row)

    // sliding 3-max over the 4 positions
    const float p01 = fmaxf(v.x, v.y);
    const float p12 = fmaxf(v.y, v.z);
    const float p23 = fmaxf(v.z, v.w);
    const float m0 = fmaxf(left, p01);
    const float m1 = fmaxf(p01, v.z);
    const float m2 = fmaxf(p12, v.w);
    const float m3 = fmaxf(p23, right);

    // NMS score: x where local max else 0
    const float s0 = (v.x == m0) ? v.x : 0.0f;
    const float s1 = (v.y == m1) ? v.y : 0.0f;
    const float s2 = (v.z == m2) ? v.z : 0.0f;
    const float s3 = (v.w == m3) ? v.w : 0.0f;

    // quad top-2 (>= keeps lower index on ties); a 4-window holds <=2 local maxima
    const bool  a01 = s0 >= s1;
    const float hiA = a01 ? s0 : s1;   const int hiAi = a01 ? p     : p + 1;
    const float loA = a01 ? s1 : s0;   const int loAi = a01 ? p + 1 : p;
    const bool  a23 = s2 >= s3;
    const float hiB = a23 ? s2 : s3;   const int hiBi = a23 ? p + 2 : p + 3;
    const float loB = a23 ? s3 : s2;   const int loBi = a23 ? p + 3 : p + 2;

    const bool  ab  = hiA >= hiB;
    const float c1  = ab ? hiA : hiB;  const int c1i = ab ? hiAi : hiBi;
    const bool  sb  = ab ? (loA >= hiB) : (hiA >= loB);
    const float c2  = ab ? (sb ? loA : hiB) : (sb ? hiA : loB);
    const int   c2i = ab ? (sb ? loAi : hiBi) : (sb ? hiAi : loBi);

    insert3_fast(c1, c1i, v0, i0, v1, i1, v2, i2);
    insert3_fast(c2, c2i, v0, i0, v1, i1, v2, i2);
  }

  // wave-level tree merge (64 lanes) — no LDS, no barrier
#pragma unroll
  for (int off = 32; off > 0; off >>= 1) {
    float ov0 = __shfl_down(v0, off);
    int   oi0 = __shfl_down(i0, off);
    float ov1 = __shfl_down(v1, off);
    int   oi1 = __shfl_down(i1, off);
    float ov2 = __shfl_down(v2, off);
    int   oi2 = __shfl_down(i2, off);
    if (lane + off < 64) {
      insert3_full(ov0, oi0, v0, i0, v1, i1, v2, i2);
      insert3_full(ov1, oi1, v0, i0, v1, i1, v2, i2);
      insert3_full(ov2, oi2, v0, i0, v1, i1, v2, i2);
    }
  }

  if (lane == 0) {
    float* o = ws + (size_t)chunk * 8;          // 32 B per chunk partial
    float4 vv; vv.x = v0; vv.y = v1; vv.z = v2; vv.w = 0.0f;
    *(float4*)o = vv;
    int4 ii; ii.x = i0; ii.y = i1; ii.z = i2; ii.w = 0;
    *(int4*)(o + 4) = ii;
  }
}

__global__ __launch_bounds__(BLOCK)
void peaks_pass2(const float* __restrict__ x, const float* __restrict__ ws,
                 float* __restrict__ out, int rows) {
  const int row = blockIdx.x * BLOCK + threadIdx.x;
  if (row >= rows) return;

  float v0 = -INFINITY, v1 = -INFINITY, v2 = -INFINITY;
  int   i0 = INT_MAX,   i1 = INT_MAX,   i2 = INT_MAX;

#pragma unroll
  for (int c = 0; c < CPR; ++c) {               // ascending chunk order: ties -> lower index
    const float* o = ws + ((size_t)row * CPR + c) * 8;
    const float4 vv = *(const float4*)o;
    const int4   ii = *(const int4*)(o + 4);
    insert3_full(vv.x, ii.x, v0, i0, v1, i1, v2, i2);
    insert3_full(vv.y, ii.y, v0, i0, v1, i1, v2, i2);
    insert3_full(vv.z, ii.z, v0, i0, v1, i1, v2, i2);
  }

  const float* __restrict__ xr = x + (size_t)row * PW;
  float* __restrict__ nb = out;                      // neighbor_score
  float* __restrict__ ts = out + (size_t)rows * 3;   // topk_scores
  float* __restrict__ ti = out + (size_t)rows * 6;   // topk_index (as float)

  const int top = i0;
#pragma unroll
  for (int k = 0; k < 3; ++k) {
    int idx = top - 1 + k;
    idx = idx < 0 ? 0 : (idx > PW - 1 ? PW - 1 : idx);
    nb[row * 3 + k] = xr[idx];
  }
  ts[row * 3 + 0] = v0;
  ts[row * 3 + 1] = v1;
  ts[row * 3 + 2] = v2;
  ti[row * 3 + 0] = (float)(i0 - PNLAG);
  ti[row * 3 + 1] = (float)(i1 - PNLAG);
  ti[row * 3 + 2] = (float)(i2 - PNLAG);
}

extern "C" void kernel_launch(void* const* d_in, const int* in_sizes, int n_in,
                              void* d_out, int out_size, void* d_ws, size_t ws_size,
                              hipStream_t stream) {
  const float* x = (const float*)d_in[0];
  float* out = (float*)d_out;
  float* ws  = (float*)d_ws;                    // uses rows*CPR*32 B = 512 KB
  const int rows = in_sizes[0] / PW;            // 4096
  const int n4   = rows * (PW / 4);             // total float4 count = 8M

  // Instrumentation dispatch: known-good streaming pattern on the same buffer.
  // Writes only into ws[0..32KB), which pass1 fully overwrites next.
  bw_probe<<<PROBE_BLOCKS, BLOCK, 0, stream>>>((const float4*)x, ws, n4);

  peaks_pass1<<<rows * CPR / NW, BLOCK, 0, stream>>>(x, ws);
  peaks_pass2<<<(rows + BLOCK - 1) / BLOCK, BLOCK, 0, stream>>>(x, ws, out, rows);
}

// Round 6
// 251.733 us; speedup vs baseline: 1.0696x; 1.0696x over previous
//
#include <hip/hip_runtime.h>
#include <climits>
#include <cmath>

// DetectPeaks: xcorr [16,1,256,8192] f32 -> (neighbor_score, topk_scores, topk_index), each [rows,3]
// rows = 4096, W = 8192.
// Round-10: PROBE-SHAPED pass1. Round-5's instrumentation: canonical grid-stride float4
// streaming (bw_probe) ran ~45-49 us (~2.7-3 TB/s) on the same buffer in the same window,
// while pass1 ran 81 us (~1.65 TB/s effective) -- kernel-side 2x remains, and the harness
// contributes a fixed ~139 us/iter of restore traffic (the env streaming ceiling is ~3 TB/s,
// not 6.3). Structure (coupling/MLP/occupancy) exonerated in rounds 0-4; the surviving delta
// is the probe's MICRO-shape: tiny tight loop, 1 load in flight, minimal work per load,
// 2048-block residency, plain launch bounds. This round ports the real computation into
// exactly that shape: #pragma unroll 1 inner loop, cur/nxt regs only (VGPR ~32), per-chunk
// tree merge unchanged. bw_probe dispatch dropped (reclaims its ~45 us from the metric).

#define PW    8192
#define PNLAG (PW / 2)
#define BLOCK 256
#define NW    4                   // waves per block
#define CHUNK 2048                // elements per chunk (one ws partial per chunk)
#define CPR   4                   // chunks per row
#define SEGS  8                   // tight-loop iterations per chunk (1 KB / 256 elems each)
#define GRID1 2048                // pass-1 blocks: 8/CU residency like the probe
#define NCHUNK (4096 * CPR)       // 16384
#define TOTW  (GRID1 * NW)        // 8192 waves -> 2 chunks per wave

__device__ __forceinline__ bool better(float av, int ai, float bv, int bi) {
  return (av > bv) || ((av == bv) && (ai < bi));   // lax.top_k: ties -> lower index
}

__device__ __forceinline__ void insert3_full(float v, int i,
                                             float &v0, int &i0,
                                             float &v1, int &i1,
                                             float &v2, int &i2) {
  if (better(v, i, v2, i2)) {
    if (better(v, i, v1, i1)) {
      if (better(v, i, v0, i0)) {
        v2 = v1; i2 = i1; v1 = v0; i1 = i0; v0 = v; i0 = i;
      } else {
        v2 = v1; i2 = i1; v1 = v; i1 = i;
      }
    } else {
      v2 = v; i2 = i;
    }
  }
}

// Exact float ties between distinct lags have ~0 probability; strict > suffices.
// Candidates arrive in ascending-index order per lane => incumbent-wins keeps lower index.
__device__ __forceinline__ void insert3_fast(float c, int ci,
                                             float &v0, int &i0,
                                             float &v1, int &i1,
                                             float &v2, int &i2) {
  const bool b2 = c > v2;
  const bool b1 = c > v1;
  const bool b0 = c > v0;
  v2 = b1 ? v1 : (b2 ? c : v2);  i2 = b1 ? i1 : (b2 ? ci : i2);
  v1 = b0 ? v0 : (b1 ? c : v1);  i1 = b0 ? i0 : (b1 ? ci : i1);
  v0 = b0 ? c  : v0;             i0 = b0 ? ci : i0;
}

__global__ __launch_bounds__(BLOCK)
void peaks_pass1(const float* __restrict__ x, float* __restrict__ ws) {
  const int t    = threadIdx.x;
  const int lane = t & 63;
  const int wave = t >> 6;
  const int wgid = blockIdx.x * NW + wave;       // 0..8191

  // grid-stride over chunks, probe-style: each wave handles 2 independent chunks
  for (int chunk = wgid; chunk < NCHUNK; chunk += TOTW) {
    const int row  = chunk >> 2;
    const int c    = chunk & 3;
    const int base = c * CHUNK;
    const float* __restrict__ xr = x + (size_t)row * PW;

    // chunk-edge halos (row edges pad -inf per torch max_pool2d); wave-uniform loads
    const float edgeL = (base > 0)          ? xr[base - 1]     : -INFINITY;
    const float edgeR = (base + CHUNK < PW) ? xr[base + CHUNK] : -INFINITY;

    float v0 = -INFINITY, v1 = -INFINITY, v2 = -INFINITY;
    int   i0 = INT_MAX,   i1 = INT_MAX,   i2 = INT_MAX;

    // tight loop, probe micro-shape: one 1 KB wave-load per iteration, cur/nxt regs only
    float4 cur = *(const float4*)(xr + base + lane * 4);
    float carry = edgeL;                         // element (p-1) for lane 0

#pragma unroll 1
    for (int s = 0; s < SEGS; ++s) {
      const bool last = (s == SEGS - 1);         // wave-uniform
      float4 nxt = cur;
      if (!last)
        nxt = *(const float4*)(xr + base + (s + 1) * 256 + lane * 4);

      // halos: left = element p-1, right = element p+4
      float left = __shfl_up(cur.w, 1);
      if (lane == 0) left = carry;
      const float nf = last ? edgeR : __shfl(nxt.x, 0);
      float right = __shfl_down(cur.x, 1);
      if (lane == 63) right = nf;
      carry = __shfl(cur.w, 63);

      const int p = base + s * 256 + lane * 4;   // first element index of this quad (in-row)

      // sliding 3-max over the 4 positions
      const float p01 = fmaxf(cur.x, cur.y);
      const float p12 = fmaxf(cur.y, cur.z);
      const float p23 = fmaxf(cur.z, cur.w);
      const float m0 = fmaxf(left, p01);
      const float m1 = fmaxf(p01, cur.z);
      const float m2 = fmaxf(p12, cur.w);
      const float m3 = fmaxf(p23, right);

      // NMS score: x where local max else 0
      const float s0 = (cur.x == m0) ? cur.x : 0.0f;
      const float s1 = (cur.y == m1) ? cur.y : 0.0f;
      const float s2 = (cur.z == m2) ? cur.z : 0.0f;
      const float s3 = (cur.w == m3) ? cur.w : 0.0f;

      // quad top-2 (>= keeps lower index on ties); a 4-window holds <=2 local maxima
      const bool  a01 = s0 >= s1;
      const float hiA = a01 ? s0 : s1;   const int hiAi = a01 ? p     : p + 1;
      const float loA = a01 ? s1 : s0;   const int loAi = a01 ? p + 1 : p;
      const bool  a23 = s2 >= s3;
      const float hiB = a23 ? s2 : s3;   const int hiBi = a23 ? p + 2 : p + 3;
      const float loB = a23 ? s3 : s2;   const int loBi = a23 ? p + 3 : p + 2;

      const bool  ab  = hiA >= hiB;
      const float c1  = ab ? hiA : hiB;  const int c1i = ab ? hiAi : hiBi;
      const bool  sb  = ab ? (loA >= hiB) : (hiA >= loB);
      const float c2  = ab ? (sb ? loA : hiB) : (sb ? hiA : loB);
      const int   c2i = ab ? (sb ? loAi : hiBi) : (sb ? hiAi : loBi);

      insert3_fast(c1, c1i, v0, i0, v1, i1, v2, i2);
      insert3_fast(c2, c2i, v0, i0, v1, i1, v2, i2);

      cur = nxt;
    }

    // wave-level tree merge (64 lanes) — once per chunk
#pragma unroll
    for (int off = 32; off > 0; off >>= 1) {
      float ov0 = __shfl_down(v0, off);
      int   oi0 = __shfl_down(i0, off);
      float ov1 = __shfl_down(v1, off);
      int   oi1 = __shfl_down(i1, off);
      float ov2 = __shfl_down(v2, off);
      int   oi2 = __shfl_down(i2, off);
      if (lane + off < 64) {
        insert3_full(ov0, oi0, v0, i0, v1, i1, v2, i2);
        insert3_full(ov1, oi1, v0, i0, v1, i1, v2, i2);
        insert3_full(ov2, oi2, v0, i0, v1, i1, v2, i2);
      }
    }

    if (lane == 0) {
      float* o = ws + (size_t)chunk * 8;         // 32 B per chunk partial
      float4 vv; vv.x = v0; vv.y = v1; vv.z = v2; vv.w = 0.0f;
      *(float4*)o = vv;
      int4 ii; ii.x = i0; ii.y = i1; ii.z = i2; ii.w = 0;
      *(int4*)(o + 4) = ii;
    }
  }
}

__global__ __launch_bounds__(BLOCK)
void peaks_pass2(const float* __restrict__ x, const float* __restrict__ ws,
                 float* __restrict__ out, int rows) {
  const int row = blockIdx.x * BLOCK + threadIdx.x;
  if (row >= rows) return;

  float v0 = -INFINITY, v1 = -INFINITY, v2 = -INFINITY;
  int   i0 = INT_MAX,   i1 = INT_MAX,   i2 = INT_MAX;

#pragma unroll
  for (int c = 0; c < CPR; ++c) {                // ascending chunk order: ties -> lower index
    const float* o = ws + ((size_t)row * CPR + c) * 8;
    const float4 vv = *(const float4*)o;
    const int4   ii = *(const int4*)(o + 4);
    insert3_full(vv.x, ii.x, v0, i0, v1, i1, v2, i2);
    insert3_full(vv.y, ii.y, v0, i0, v1, i1, v2, i2);
    insert3_full(vv.z, ii.z, v0, i0, v1, i1, v2, i2);
  }

  const float* __restrict__ xr = x + (size_t)row * PW;
  float* __restrict__ nb = out;                      // neighbor_score
  float* __restrict__ ts = out + (size_t)rows * 3;   // topk_scores
  float* __restrict__ ti = out + (size_t)rows * 6;   // topk_index (as float)

  const int top = i0;
#pragma unroll
  for (int k = 0; k < 3; ++k) {
    int idx = top - 1 + k;
    idx = idx < 0 ? 0 : (idx > PW - 1 ? PW - 1 : idx);
    nb[row * 3 + k] = xr[idx];
  }
  ts[row * 3 + 0] = v0;
  ts[row * 3 + 1] = v1;
  ts[row * 3 + 2] = v2;
  ti[row * 3 + 0] = (float)(i0 - PNLAG);
  ti[row * 3 + 1] = (float)(i1 - PNLAG);
  ti[row * 3 + 2] = (float)(i2 - PNLAG);
}

extern "C" void kernel_launch(void* const* d_in, const int* in_sizes, int n_in,
                              void* d_out, int out_size, void* d_ws, size_t ws_size,
                              hipStream_t stream) {
  const float* x = (const float*)d_in[0];
  float* out = (float*)d_out;
  float* ws  = (float*)d_ws;                    // uses NCHUNK*32 B = 512 KB
  const int rows = in_sizes[0] / PW;            // 4096

  peaks_pass1<<<GRID1, BLOCK, 0, stream>>>(x, ws);
  peaks_pass2<<<(rows + BLOCK - 1) / BLOCK, BLOCK, 0, stream>>>(x, ws, out, rows);
}

// Round 7
// 234.543 us; speedup vs baseline: 1.1480x; 1.0733x over previous
//
#include <hip/hip_runtime.h>
#include <climits>
#include <cmath>

// DetectPeaks: xcorr [16,1,256,8192] f32 -> (neighbor_score, topk_scores, topk_index), each [rows,3]
// rows = 4096, W = 8192. One block (4 waves) per row; wave w owns elements [w*2048, (w+1)*2048).
// Round-11: round-0 DMA staging (global_load_lds width=16: fire-and-forget, 32 KB/block in
// flight, zero VGPR) + per-wave COUNTED-vmcnt consumption (T3/T4 pattern) instead of the
// block-wide __syncthreads drain. Rounds 0-6 established the additive model: mem ~48-60us +
// VALU ~21-27us + DS/waits never overlap (every prior structure either consumed loads
// immediately, had loads compiler-sunk, or full-drained at a barrier). Here compute on seg s
// begins as soon as DMAs 0..s+1 land (s_waitcnt vmcnt(6-s)) while segs s+2..7 stay in flight.
// Halos via shfl + single-lane LDS fixups (kills round-0's 1.57M 8-way bank conflicts).
// Edge loads issue FIRST (oldest in vmcnt order -> per-wave edge count cancels in the wait
// arithmetic); sched_barrier(0) pins the issue clusters.

#define PW    8192
#define PNLAG (PW / 2)
#define BLOCK 256
#define NW    4                 // waves per block
#define SEGS  8                 // 256-elem segments per wave (2048 elems total)

typedef __attribute__((address_space(1))) const void global_cv;
typedef __attribute__((address_space(3))) void lds_v;

#define WAIT_VM(n) asm volatile("s_waitcnt vmcnt(" #n ")" ::: "memory")

__device__ __forceinline__ bool better(float av, int ai, float bv, int bi) {
  return (av > bv) || ((av == bv) && (ai < bi));   // lax.top_k: ties -> lower index
}

__device__ __forceinline__ void insert3_full(float v, int i,
                                             float &v0, int &i0,
                                             float &v1, int &i1,
                                             float &v2, int &i2) {
  if (better(v, i, v2, i2)) {
    if (better(v, i, v1, i1)) {
      if (better(v, i, v0, i0)) {
        v2 = v1; i2 = i1; v1 = v0; i1 = i0; v0 = v; i0 = i;
      } else {
        v2 = v1; i2 = i1; v1 = v; i1 = i;
      }
    } else {
      v2 = v; i2 = i;
    }
  }
}

// Exact float ties between distinct lags have ~0 probability; strict > suffices.
// Candidates arrive in ascending-index order per lane => incumbent-wins keeps lower index.
__device__ __forceinline__ void insert3_fast(float c, int ci,
                                             float &v0, int &i0,
                                             float &v1, int &i1,
                                             float &v2, int &i2) {
  const bool b2 = c > v2;
  const bool b1 = c > v1;
  const bool b0 = c > v0;
  v2 = b1 ? v1 : (b2 ? c : v2);  i2 = b1 ? i1 : (b2 ? ci : i2);
  v1 = b0 ? v0 : (b1 ? c : v1);  i1 = b0 ? i0 : (b1 ? ci : i1);
  v0 = b0 ? c  : v0;             i0 = b0 ? ci : i0;
}

__global__ __launch_bounds__(BLOCK)
void detect_peaks_kernel(const float* __restrict__ x,
                         float* __restrict__ out,
                         int rows) {
  __shared__ float sx[PW];       // full row, staged by DMA
  __shared__ float rv[NW * 3];   // per-wave top-3 values
  __shared__ int   ri[NW * 3];   // per-wave top-3 indices

  const int row  = blockIdx.x;
  const int t    = threadIdx.x;
  const int lane = t & 63;
  const int wave = t >> 6;
  const float* __restrict__ xr = x + (size_t)row * PW;

  const int W = wave * 2048;     // first element of this wave's span

  // ---- edge loads FIRST (oldest vmem ops; per-wave count E cancels in wait arithmetic) ----
  const float edgeL = (W > 0)         ? xr[W - 1]    : -INFINITY;
  const float edgeR = (W + 2048 < PW) ? xr[W + 2048] : -INFINITY;
  __builtin_amdgcn_sched_barrier(0);

  // ---- async DMA: 8 fire-and-forget global_load_lds_dwordx4 per wave (8 KB in flight) ----
  // HW semantics: per-lane global vaddr; LDS dst = wave-uniform base + lane*16.
#pragma unroll
  for (int s = 0; s < SEGS; ++s) {
    const float* gsrc = xr + (size_t)(W + s * 256 + lane * 4);
    float*       ldst = sx + (size_t)(W + s * 256);           // wave-uniform base
    __builtin_amdgcn_global_load_lds((global_cv*)gsrc, (lds_v*)ldst, 16, 0, 0);
  }
  __builtin_amdgcn_sched_barrier(0);

  float v0 = -INFINITY, v1 = -INFINITY, v2 = -INFINITY;
  int   i0 = INT_MAX,   i1 = INT_MAX,   i2 = INT_MAX;

  // ---- counted-vmcnt consumption: seg s needs DMAs 0..s+1 landed (one-seg lookahead for
  // the right halo). With E edge loads oldest and 8 DMAs outstanding: allowed = 6-s. ----
#pragma unroll
  for (int s = 0; s < SEGS; ++s) {
    switch (s) {                 // literal immediates; folds under full unroll
      case 0: WAIT_VM(6); break;
      case 1: WAIT_VM(5); break;
      case 2: WAIT_VM(4); break;
      case 3: WAIT_VM(3); break;
      case 4: WAIT_VM(2); break;
      case 5: WAIT_VM(1); break;
      default: WAIT_VM(0); break;
    }

    const int segbase = W + s * 256;
    const int p = segbase + lane * 4;             // first element of this lane's quad
    const float4 v = *(const float4*)(sx + p);    // ds_read_b128, lane-contiguous (2-way free)

    // halos: left = elem p-1, right = elem p+4. Interior via shfl; lane-boundary via
    // single-lane LDS fixup (1 active lane -> no bank conflict). Right needs seg s+1 (waited).
    float left = __shfl_up(v.w, 1);
    if (lane == 0) left = (s == 0) ? edgeL : sx[segbase - 1];
    float right = __shfl_down(v.x, 1);
    if (lane == 63) right = (s == SEGS - 1) ? edgeR : sx[segbase + 256];

    // sliding 3-max over the 4 positions
    const float p01 = fmaxf(v.x, v.y);
    const float p12 = fmaxf(v.y, v.z);
    const float p23 = fmaxf(v.z, v.w);
    const float m0 = fmaxf(left, p01);
    const float m1 = fmaxf(p01, v.z);
    const float m2 = fmaxf(p12, v.w);
    const float m3 = fmaxf(p23, right);

    // NMS score: x where local max else 0
    const float s0 = (v.x == m0) ? v.x : 0.0f;
    const float s1 = (v.y == m1) ? v.y : 0.0f;
    const float s2 = (v.z == m2) ? v.z : 0.0f;
    const float s3 = (v.w == m3) ? v.w : 0.0f;

    // quad top-2 (>= keeps lower index on ties); a 4-window holds <=2 local maxima
    const bool  a01 = s0 >= s1;
    const float hiA = a01 ? s0 : s1;   const int hiAi = a01 ? p     : p + 1;
    const float loA = a01 ? s1 : s0;   const int loAi = a01 ? p + 1 : p;
    const bool  a23 = s2 >= s3;
    const float hiB = a23 ? s2 : s3;   const int hiBi = a23 ? p + 2 : p + 3;
    const float loB = a23 ? s3 : s2;   const int loBi = a23 ? p + 3 : p + 2;

    const bool  ab  = hiA >= hiB;
    const float c1  = ab ? hiA : hiB;  const int c1i = ab ? hiAi : hiBi;
    const bool  sb  = ab ? (loA >= hiB) : (hiA >= loB);
    const float c2  = ab ? (sb ? loA : hiB) : (sb ? hiA : loB);
    const int   c2i = ab ? (sb ? loAi : hiBi) : (sb ? hiAi : loBi);

    insert3_fast(c1, c1i, v0, i0, v1, i1, v2, i2);
    insert3_fast(c2, c2i, v0, i0, v1, i1, v2, i2);
  }

  // ---- wave-level tree merge (64 lanes) ----
#pragma unroll
  for (int off = 32; off > 0; off >>= 1) {
    float ov0 = __shfl_down(v0, off);
    int   oi0 = __shfl_down(i0, off);
    float ov1 = __shfl_down(v1, off);
    int   oi1 = __shfl_down(i1, off);
    float ov2 = __shfl_down(v2, off);
    int   oi2 = __shfl_down(i2, off);
    if (lane + off < 64) {
      insert3_full(ov0, oi0, v0, i0, v1, i1, v2, i2);
      insert3_full(ov1, oi1, v0, i0, v1, i1, v2, i2);
      insert3_full(ov2, oi2, v0, i0, v1, i1, v2, i2);
    }
  }

  if (lane == 0) {
    rv[wave * 3 + 0] = v0; ri[wave * 3 + 0] = i0;
    rv[wave * 3 + 1] = v1; ri[wave * 3 + 1] = i1;
    rv[wave * 3 + 2] = v2; ri[wave * 3 + 2] = i2;
  }
  __syncthreads();   // everything long since landed; full drain is free here

  if (t == 0) {
#pragma unroll
    for (int w = 1; w < NW; ++w) {
      insert3_full(rv[w * 3 + 0], ri[w * 3 + 0], v0, i0, v1, i1, v2, i2);
      insert3_full(rv[w * 3 + 1], ri[w * 3 + 1], v0, i0, v1, i1, v2, i2);
      insert3_full(rv[w * 3 + 2], ri[w * 3 + 2], v0, i0, v1, i1, v2, i2);
    }

    float* __restrict__ nb = out;                      // neighbor_score
    float* __restrict__ ts = out + (size_t)rows * 3;   // topk_scores
    float* __restrict__ ti = out + (size_t)rows * 6;   // topk_index (as float)

    const int top = i0;
#pragma unroll
    for (int k = 0; k < 3; ++k) {
      int idx = top - 1 + k;
      idx = idx < 0 ? 0 : (idx > PW - 1 ? PW - 1 : idx);
      nb[row * 3 + k] = sx[idx];                       // full row is in LDS
    }
    ts[row * 3 + 0] = v0;
    ts[row * 3 + 1] = v1;
    ts[row * 3 + 2] = v2;
    ti[row * 3 + 0] = (float)(i0 - PNLAG);
    ti[row * 3 + 1] = (float)(i1 - PNLAG);
    ti[row * 3 + 2] = (float)(i2 - PNLAG);
  }
}

extern "C" void kernel_launch(void* const* d_in, const int* in_sizes, int n_in,
                              void* d_out, int out_size, void* d_ws, size_t ws_size,
                              hipStream_t stream) {
  const float* x = (const float*)d_in[0];
  float* out = (float*)d_out;
  const int rows = in_sizes[0] / PW;   // 4096
  detect_peaks_kernel<<<rows, BLOCK, 0, stream>>>(x, out, rows);
}